// Round 5
// baseline (249.171 us; speedup 1.0000x reference)
//
#include <hip/hip_runtime.h>

// Scaled dot-product attention, B=2 H=12 S=4096 d=64, fp32 in/out.
// Round 5: LDS pipe was the wall (~87% busy incl. 4-way conflicts on 32-row
// fragment reads). Changes:
//  - Fragment-ordered K/V^T/P LDS images: every MFMA fragment read is a
//    contiguous wave64 ds_read_b128 (conflict-clean per m134), no swizzle.
//  - 2 q-subtiles per wave, 2 waves/block (BM=128): kf/vf read once, used 2x.
//  - preconv split into K-blocks and V-blocks (blockIdx.z) for 2x parallelism.
// Layouts (m74/m101 C-map, verified in rounds 3-4):
//  A 32x32x16: A[m=lane&31][k=(lane>>5)*8+j];  B: B[k=(lane>>5)*8+j][n=lane&31]
//  C/D: col=lane&31, row=(reg&3)+8*(reg>>2)+4*(lane>>5)

constexpr int Sseq = 4096;
constexpr int Dh   = 64;
constexpr int BM   = 128;         // q rows per block: 2 waves x 64 (2 subtiles of 32)
constexpr int BN   = 64;          // keys per K-loop iteration
constexpr int NT   = Sseq / BN;   // 64 key-tiles per head

typedef short bf16x8 __attribute__((ext_vector_type(8)));
typedef float f32x4  __attribute__((ext_vector_type(4)));
typedef float f32x16 __attribute__((ext_vector_type(16)));

__device__ __forceinline__ unsigned short f2bf(float x) {
    union { float f; unsigned int u; } v; v.f = x;
    unsigned int r = v.u + 0x7fffu + ((v.u >> 16) & 1u);  // RNE
    return (unsigned short)(r >> 16);
}

// pack two f32 -> bf16x2 (a -> low16, b -> high16), round-half-up
__device__ __forceinline__ unsigned int packbf2(float a, float b) {
    unsigned int ua = __float_as_uint(a) + 0x8000u;
    unsigned int ub = __float_as_uint(b) + 0x8000u;
    return __builtin_amdgcn_perm(ub, ua, 0x07060302u);
}

#if __has_builtin(__builtin_amdgcn_exp2f)
#define EXP2(x) __builtin_amdgcn_exp2f(x)
#else
#define EXP2(x) exp2f(x)
#endif

__device__ __forceinline__ void gld16(const void* g, void* l) {
    __builtin_amdgcn_global_load_lds(
        (const __attribute__((address_space(1))) void*)g,
        (__attribute__((address_space(3))) void*)l, 16, 0, 0);
}

// ---------------- pre-pass: fragment-ordered bf16 images ---------------------
// ws per (bh,kb): [ K image 8192 B | V^T image 8192 B ].
// K image chunk (mt*4+kc) holds, at lane slot l (16 B):
//   K[key=32*mt+(l&31)][d = 16*kc + 8*(l>>5) + 0..7]
// V image chunk (nt*4+kc) holds: V^T[d=32*nt+(l&31)][key = 16*kc + 8*(l>>5) + 0..7]
__global__ __launch_bounds__(256)
void preconv_kernel(const float* __restrict__ K, const float* __restrict__ V,
                    unsigned short* __restrict__ ws)
{
    const int kb = blockIdx.x, bh = blockIdx.y, tid = threadIdx.x;
    unsigned short* kimg = ws + (size_t)(bh * NT + kb) * 8192;

    if (blockIdx.z == 0) {
        // ---- K image (no LDS): direct fragment-order scatter of uint2
        const float4* k4 = reinterpret_cast<const float4*>(K + ((size_t)bh * Sseq + kb * BN) * Dh);
        float4 kv[4];
        #pragma unroll
        for (int it = 0; it < 4; ++it) kv[it] = k4[it * 256 + tid];
        #pragma unroll
        for (int it = 0; it < 4; ++it) {
            const int f  = it * 256 + tid;
            const int r  = f >> 4;           // key 0..63
            const int c4 = (f & 15) * 4;     // d   0..60
            const int chunk = (r >> 5) * 4 + (c4 >> 4);
            const int ln    = ((c4 >> 3) & 1) * 32 + (r & 31);
            uint2 p;
            p.x = packbf2(kv[it].x, kv[it].y);
            p.y = packbf2(kv[it].z, kv[it].w);
            *reinterpret_cast<uint2*>(&kimg[chunk * 512 + ln * 8 + (c4 & 7)]) = p;
        }
    } else {
        // ---- V^T image via LDS transpose (tV[d*72 + key], 144B rows, 16B-aligned)
        __shared__ unsigned short tV[64 * 72];
        const float4* v4 = reinterpret_cast<const float4*>(V + ((size_t)bh * Sseq + kb * BN) * Dh);
        float4 vv[4];
        #pragma unroll
        for (int it = 0; it < 4; ++it) vv[it] = v4[it * 256 + tid];
        #pragma unroll
        for (int it = 0; it < 4; ++it) {
            const int f  = it * 256 + tid;
            const int r  = f >> 4;
            const int c4 = (f & 15) * 4;
            tV[(c4 + 0) * 72 + r] = f2bf(vv[it].x);
            tV[(c4 + 1) * 72 + r] = f2bf(vv[it].y);
            tV[(c4 + 2) * 72 + r] = f2bf(vv[it].z);
            tV[(c4 + 3) * 72 + r] = f2bf(vv[it].w);
        }
        __syncthreads();
        unsigned short* vimg = kimg + 4096;
        #pragma unroll
        for (int i = 0; i < 2; ++i) {
            const int c  = i * 256 + tid;           // chunk-slot 0..511
            const int nt = c >> 8, kc = (c >> 6) & 3, l = c & 63;
            const uint4 x = *reinterpret_cast<const uint4*>(
                &tV[(32 * nt + (l & 31)) * 72 + 16 * kc + 8 * (l >> 5)]);
            *reinterpret_cast<uint4*>(&vimg[c * 8]) = x;   // coalesced
        }
    }
}

// ---------------- main flash-attention kernel --------------------------------
__global__ __launch_bounds__(128, 2)
void fattn_kernel(const float* __restrict__ Q, const unsigned short* __restrict__ ws,
                  float* __restrict__ O)
{
    __shared__ unsigned short sKV[2][8192];      // dbuf: [K 8KB | V^T 8KB], frag order
    __shared__ unsigned short sP [2][2][2048];   // [wave][subtile]: P in af-frag order

    const int tid  = threadIdx.x;
    const int wave = tid >> 6;     // 0..1
    const int lane = tid & 63;
    const int lo32 = lane & 31;
    const int half = lane >> 5;

    const int qblk = blockIdx.x;   // 0..31
    const int bh   = blockIdx.y;   // 0..23

    const float* gQ = Q + (size_t)bh * Sseq * Dh;
    float*       gO = O + (size_t)bh * Sseq * Dh;

    // Q as B-operand of S^T = K·Q^T: lane holds Q[q][d = 16kc + 8half + j]
    const float qscale = 0.18033688011112042f;  // (1/sqrt(64)) * log2(e)
    bf16x8 qf[2][4];
    #pragma unroll
    for (int u = 0; u < 2; ++u) {
        const int qrow = qblk * BM + wave * 64 + u * 32 + lo32;
        const float* qp = gQ + (size_t)qrow * Dh + half * 8;
        #pragma unroll
        for (int kc = 0; kc < 4; ++kc) {
            float4 a = *reinterpret_cast<const float4*>(qp + kc * 16);
            float4 b = *reinterpret_cast<const float4*>(qp + kc * 16 + 4);
            qf[u][kc][0] = (short)f2bf(a.x * qscale);
            qf[u][kc][1] = (short)f2bf(a.y * qscale);
            qf[u][kc][2] = (short)f2bf(a.z * qscale);
            qf[u][kc][3] = (short)f2bf(a.w * qscale);
            qf[u][kc][4] = (short)f2bf(b.x * qscale);
            qf[u][kc][5] = (short)f2bf(b.y * qscale);
            qf[u][kc][6] = (short)f2bf(b.z * qscale);
            qf[u][kc][7] = (short)f2bf(b.w * qscale);
        }
    }

    f32x16 accO[2][2];   // [subtile][d-half], C-layout
    #pragma unroll
    for (int u = 0; u < 2; ++u)
        #pragma unroll
        for (int nt = 0; nt < 2; ++nt)
            #pragma unroll
            for (int i = 0; i < 16; ++i) accO[u][nt][i] = 0.f;
    float rsum[2] = {0.f, 0.f};

    const char* img = (const char*)(ws + (size_t)bh * NT * 8192);
    const int loff = lane * 16;

    // prologue: DMA tile 0 -> buf 0 (each wave stages 8 KB, contiguous)
    #pragma unroll
    for (int c = 0; c < 8; ++c) {
        const int off = wave * 8192 + c * 1024;
        gld16(img + off + loff, (char*)sKV[0] + off);
    }
    __syncthreads();

    for (int kb = 0; kb < NT; ++kb) {
        const int buf = kb & 1;
        const unsigned short* sK  = sKV[buf];
        const unsigned short* sVt = sKV[buf] + 4096;
        unsigned short* sP0 = sP[wave][0];
        unsigned short* sP1 = sP[wave][1];

        if (kb + 1 < NT) {  // prefetch next tile into other buffer
            const char* nimg = img + (size_t)(kb + 1) * 16384;
            #pragma unroll
            for (int c = 0; c < 8; ++c) {
                const int off = wave * 8192 + c * 1024;
                gld16(nimg + off + loff, (char*)sKV[buf ^ 1] + off);
            }
        }

        // ---- S^T = K·Q^T per 32-key tile; kf read once, used for both subtiles
        #pragma unroll
        for (int mt = 0; mt < 2; ++mt) {
            f32x16 c0, c1;
            #pragma unroll
            for (int i = 0; i < 16; ++i) { c0[i] = 0.f; c1[i] = 0.f; }
            #pragma unroll
            for (int kc = 0; kc < 4; ++kc) {
                const bf16x8 kf = *reinterpret_cast<const bf16x8*>(&sK[(mt * 4 + kc) * 512 + lane * 8]);
                c0 = __builtin_amdgcn_mfma_f32_32x32x16_bf16(kf, qf[0][kc], c0, 0, 0, 0);
                c1 = __builtin_amdgcn_mfma_f32_32x32x16_bf16(kf, qf[1][kc], c1, 0, 0, 0);
            }
            #pragma unroll
            for (int u = 0; u < 2; ++u) {
                const f32x16& c = u ? c1 : c0;
                unsigned short* sPu = u ? sP1 : sP0;
                #pragma unroll
                for (int rg = 0; rg < 4; ++rg) {
                    const float p0 = EXP2(c[4 * rg + 0]);
                    const float p1 = EXP2(c[4 * rg + 1]);
                    const float p2 = EXP2(c[4 * rg + 2]);
                    const float p3 = EXP2(c[4 * rg + 3]);
                    rsum[u] += (p0 + p1) + (p2 + p3);
                    uint2 pk;
                    pk.x = packbf2(p0, p1);
                    pk.y = packbf2(p2, p3);
                    // keys 32mt+8rg+4half+0..3 -> 4-key block b; store in af-frag order
                    const int b = 8 * mt + 2 * rg + half;
                    *reinterpret_cast<uint2*>(
                        &sPu[(b >> 2) * 512 + ((b >> 1) & 1) * 256 + lo32 * 8 + (b & 1) * 4]) = pk;
                }
            }
        }

        // ---- PV: vf read once, used for both subtiles
        bf16x8 af[2][4];
        #pragma unroll
        for (int kc = 0; kc < 4; ++kc) {
            af[0][kc] = *reinterpret_cast<const bf16x8*>(&sP0[kc * 512 + lane * 8]);
            af[1][kc] = *reinterpret_cast<const bf16x8*>(&sP1[kc * 512 + lane * 8]);
        }
        #pragma unroll
        for (int nt = 0; nt < 2; ++nt) {
            #pragma unroll
            for (int kc = 0; kc < 4; ++kc) {
                const bf16x8 vf = *reinterpret_cast<const bf16x8*>(&sVt[(nt * 4 + kc) * 512 + lane * 8]);
                accO[0][nt] = __builtin_amdgcn_mfma_f32_32x32x16_bf16(af[0][kc], vf, accO[0][nt], 0, 0, 0);
                accO[1][nt] = __builtin_amdgcn_mfma_f32_32x32x16_bf16(af[1][kc], vf, accO[1][nt], 0, 0, 0);
            }
        }
        __syncthreads();  // buf readers done + prefetch DMA drained
    }

    // ---- epilogue: rowsum across halves, inv broadcast via wave-private LDS
    float* sF = (float*)sP[wave][0];
    #pragma unroll
    for (int u = 0; u < 2; ++u) {
        const float rtot = rsum[u] + __shfl_xor(rsum[u], 32);
        sF[u * 32 + lo32] = 1.0f / rtot;   // both halves write identical value
    }
    const int qwbase = qblk * BM + wave * 64;
    #pragma unroll
    for (int u = 0; u < 2; ++u) {
        #pragma unroll
        for (int nt = 0; nt < 2; ++nt) {
            #pragma unroll
            for (int r = 0; r < 16; ++r) {
                const int row = (r & 3) + 8 * (r >> 2) + 4 * half;
                gO[(size_t)(qwbase + u * 32 + row) * Dh + nt * 32 + lo32] =
                    accO[u][nt][r] * sF[u * 32 + row];
            }
        }
    }
}

// ---------------- fallback (round-1 proven kernel) if ws is too small --------
constexpr int LD = 72;
__global__ __launch_bounds__(256, 2)
void fattn_fallback(const float* __restrict__ Q, const float* __restrict__ K,
                    const float* __restrict__ V, float* __restrict__ O)
{
    __shared__ unsigned short sK [BN * LD];
    __shared__ unsigned short sVt[Dh * LD];
    __shared__ unsigned short sP [4 * 16 * LD];

    const int tid  = threadIdx.x;
    const int wave = tid >> 6;
    const int lane = tid & 63;
    const int lo   = lane & 15;
    const int quad = lane >> 4;
    const int qblk = blockIdx.x;
    const int bh   = blockIdx.y;

    const float* gQ = Q + (size_t)bh * Sseq * Dh;
    const float* gK = K + (size_t)bh * Sseq * Dh;
    const float* gV = V + (size_t)bh * Sseq * Dh;
    float*       gO = O + (size_t)bh * Sseq * Dh;

    const float qscale = 0.18033688011112042f;
    bf16x8 qf[2];
    {
        const int qrow = qblk * 64 + wave * 16 + lo;
        const float* qp = gQ + (size_t)qrow * Dh + quad * 8;
        #pragma unroll
        for (int c = 0; c < 2; ++c) {
            float4 a = *reinterpret_cast<const float4*>(qp + c * 32);
            float4 b = *reinterpret_cast<const float4*>(qp + c * 32 + 4);
            qf[c][0] = (short)f2bf(a.x * qscale); qf[c][1] = (short)f2bf(a.y * qscale);
            qf[c][2] = (short)f2bf(a.z * qscale); qf[c][3] = (short)f2bf(a.w * qscale);
            qf[c][4] = (short)f2bf(b.x * qscale); qf[c][5] = (short)f2bf(b.y * qscale);
            qf[c][6] = (short)f2bf(b.z * qscale); qf[c][7] = (short)f2bf(b.w * qscale);
        }
    }

    float m_prev[4] = {-1e30f, -1e30f, -1e30f, -1e30f};
    float lsum[4]   = {0.f, 0.f, 0.f, 0.f};
    f32x4 accv[4];
    #pragma unroll
    for (int t = 0; t < 4; ++t) accv[t] = f32x4{0.f, 0.f, 0.f, 0.f};
    unsigned short* sPw = &sP[wave * 16 * LD];

    for (int kb = 0; kb < Sseq / BN; ++kb) {
        const float4* k4 = reinterpret_cast<const float4*>(gK + (size_t)kb * BN * Dh);
        const float4* v4 = reinterpret_cast<const float4*>(gV + (size_t)kb * BN * Dh);
        #pragma unroll
        for (int it = 0; it < 4; ++it) {
            const int f   = it * 256 + tid;
            const int row = f >> 4;
            const int c4  = (f & 15) * 4;
            float4 kv = k4[f];
            unsigned int l32 = (unsigned int)f2bf(kv.x) | ((unsigned int)f2bf(kv.y) << 16);
            unsigned int h32 = (unsigned int)f2bf(kv.z) | ((unsigned int)f2bf(kv.w) << 16);
            *reinterpret_cast<uint2*>(&sK[row * LD + c4]) = make_uint2(l32, h32);
            float4 vv = v4[f];
            sVt[(c4 + 0) * LD + row] = f2bf(vv.x);
            sVt[(c4 + 1) * LD + row] = f2bf(vv.y);
            sVt[(c4 + 2) * LD + row] = f2bf(vv.z);
            sVt[(c4 + 3) * LD + row] = f2bf(vv.w);
        }
        __syncthreads();

        float sc[4][4];
        #pragma unroll
        for (int t = 0; t < 4; ++t) {
            const bf16x8 k0 = *reinterpret_cast<const bf16x8*>(&sK[(t * 16 + lo) * LD + 0  + quad * 8]);
            const bf16x8 k1 = *reinterpret_cast<const bf16x8*>(&sK[(t * 16 + lo) * LD + 32 + quad * 8]);
            f32x4 s = f32x4{0.f, 0.f, 0.f, 0.f};
            s = __builtin_amdgcn_mfma_f32_16x16x32_bf16(qf[0], k0, s, 0, 0, 0);
            s = __builtin_amdgcn_mfma_f32_16x16x32_bf16(qf[1], k1, s, 0, 0, 0);
            sc[t][0] = s[0]; sc[t][1] = s[1]; sc[t][2] = s[2]; sc[t][3] = s[3];
        }

        float bm[4];
        #pragma unroll
        for (int r = 0; r < 4; ++r)
            bm[r] = fmaxf(fmaxf(sc[0][r], sc[1][r]), fmaxf(sc[2][r], sc[3][r]));
        #pragma unroll
        for (int m = 1; m <= 8; m <<= 1) {
            #pragma unroll
            for (int r = 0; r < 4; ++r) bm[r] = fmaxf(bm[r], __shfl_xor(bm[r], m));
        }
        float m_new[4], alpha[4];
        #pragma unroll
        for (int r = 0; r < 4; ++r) {
            m_new[r] = fmaxf(m_prev[r], bm[r]);
            alpha[r] = exp2f(m_prev[r] - m_new[r]);
            m_prev[r] = m_new[r];
        }
        float ps[4][4];
        float rs[4] = {0.f, 0.f, 0.f, 0.f};
        #pragma unroll
        for (int t = 0; t < 4; ++t) {
            #pragma unroll
            for (int r = 0; r < 4; ++r) { ps[t][r] = exp2f(sc[t][r] - m_new[r]); rs[r] += ps[t][r]; }
        }
        #pragma unroll
        for (int m = 1; m <= 8; m <<= 1) {
            #pragma unroll
            for (int r = 0; r < 4; ++r) rs[r] += __shfl_xor(rs[r], m);
        }
        #pragma unroll
        for (int r = 0; r < 4; ++r) lsum[r] = lsum[r] * alpha[r] + rs[r];
        #pragma unroll
        for (int t = 0; t < 4; ++t) {
            #pragma unroll
            for (int r = 0; r < 4; ++r) accv[t][r] *= alpha[r];
        }
        #pragma unroll
        for (int t = 0; t < 4; ++t) {
            #pragma unroll
            for (int r = 0; r < 4; ++r)
                sPw[(quad * 4 + r) * LD + t * 16 + lo] = f2bf(ps[t][r]);
        }
        #pragma unroll
        for (int c = 0; c < 2; ++c) {
            const bf16x8 af = *reinterpret_cast<const bf16x8*>(&sPw[lo * LD + c * 32 + quad * 8]);
            #pragma unroll
            for (int t2 = 0; t2 < 4; ++t2) {
                const bf16x8 vf = *reinterpret_cast<const bf16x8*>(&sVt[(t2 * 16 + lo) * LD + c * 32 + quad * 8]);
                accv[t2] = __builtin_amdgcn_mfma_f32_16x16x32_bf16(af, vf, accv[t2], 0, 0, 0);
            }
        }
        __syncthreads();
    }

    const int qbase = qblk * 64 + wave * 16 + quad * 4;
    #pragma unroll
    for (int r = 0; r < 4; ++r) {
        const float inv = 1.0f / lsum[r];
        float* op = gO + (size_t)(qbase + r) * Dh;
        #pragma unroll
        for (int t2 = 0; t2 < 4; ++t2)
            op[t2 * 16 + lo] = accv[t2][r] * inv;
    }
}

extern "C" void kernel_launch(void* const* d_in, const int* in_sizes, int n_in,
                              void* d_out, int out_size, void* d_ws, size_t ws_size,
                              hipStream_t stream) {
    const float* Q = (const float*)d_in[0];
    const float* K = (const float*)d_in[1];
    const float* V = (const float*)d_in[2];
    float* O = (float*)d_out;
    const int BH = in_sizes[0] / (Sseq * Dh);  // 24
    const size_t ws_needed = (size_t)BH * NT * 16384;  // 25.2 MB
    if (ws_size >= ws_needed) {
        preconv_kernel<<<dim3(NT, BH, 2), 256, 0, stream>>>(K, V, (unsigned short*)d_ws);
        fattn_kernel<<<dim3(Sseq / BM, BH), 128, 0, stream>>>(Q, (const unsigned short*)d_ws, O);
    } else {
        fattn_fallback<<<dim3(Sseq / 64, BH), 256, 0, stream>>>(Q, K, V, O);
    }
}